// Round 4
// baseline (552.408 us; speedup 1.0000x reference)
//
#include <hip/hip_runtime.h>

// GAT fused pipeline, fp16 MFMA (16x16x32), MI355X gfx950.
// B=16, N=1024, F_in=F_out=256, H=8, ALPHA=0.2
//
// Round-4 changes:
//  - LDS <= 31KB/block (empirical ~64KB workgroup-LDS pool -> 2 blocks/CU)
//  - unpadded 64B LDS rows + XOR chunk swizzle (kills staging write conflicts)
//  - register prefetch pipeline in both K-loops (hide global latency)
//  - ml_kernel eliminated: softmax denom l_i computed inside pv via an
//    extra MFMA with an all-ones B fragment; normalize by 1/l in epilogue.
//
// ws layout: [0,64MB) WhT fp16 [B][H][F_out][N]; +67108864 ei f32; +524288 ej f32.

#define L2E 1.442695041f

typedef _Float16 half8 __attribute__((ext_vector_type(8)));
typedef __fp16 fp16x2 __attribute__((ext_vector_type(2)));
typedef float floatx4 __attribute__((ext_vector_type(4)));

#if __has_builtin(__builtin_amdgcn_exp2f)
#define EXP2F(x) __builtin_amdgcn_exp2f(x)
#else
#define EXP2F(x) exp2f(x)
#endif

static __device__ inline unsigned int pack2(float a, float b) {
    fp16x2 h = __builtin_amdgcn_cvt_pkrtz(a, b);
    return __builtin_bit_cast(unsigned int, h);
}

// swizzled LDS byte address: [row][chunk c of 16B], 64B rows (no pad),
// c' = c ^ ((row>>1)&3). Uniform bank use for both staging writes and
// b128 fragment reads (verified by hand: 8 lanes per 4-bank group).
static __device__ inline int swz(int row, int c) {
    return (row << 6) + ((((c) ^ (row >> 1)) & 3) << 4);
}

// ---------------------------------------------------------------------------
// Stage 1: WhT[b,h,o,n] = sum_f W[h,o,f]*h[b,n,f] + bW[h,o]  (fp16 out)
// + fused ei/ej epilogue. Tile 256(o) x 128(bn), K=256, BK=32, 512 thr.
__global__ __launch_bounds__(512, 4) void wh_kernel(
    const float* __restrict__ hin, const float* __restrict__ W,
    const float* __restrict__ bW, _Float16* __restrict__ WhT,
    const float* __restrict__ a1, const float* __restrict__ a2,
    float* __restrict__ ei, float* __restrict__ ej)
{
    const int bnt  = blockIdx.x;   // 0..127
    const int head = blockIdx.y;   // 0..7
    const int t    = threadIdx.x;
    const int wave = t >> 6, lane = t & 63;
    const int l15 = lane & 15, quad = lane >> 4;

    __shared__ char smem[24576];
    _Float16* As = (_Float16*)smem;            // 256 rows x 64B = 16384
    _Float16* Bs = (_Float16*)(smem + 16384);  // 128 rows x 64B = 8192
    // epilogue overlay on As region (dead after K-loop):
    float* bWs  = (float*)smem;
    float* a1s  = (float*)(smem + 1024);
    float* a2s  = (float*)(smem + 2048);
    float* red1 = (float*)(smem + 3072);
    float* red2 = (float*)(smem + 3584);

    const int bn0 = bnt * 128;
    floatx4 acc[4][4];
#pragma unroll
    for (int a = 0; a < 4; a++)
#pragma unroll
        for (int b = 0; b < 4; b++) acc[a][b] = (floatx4)0.0f;

    const int wm = (wave & 3) * 4;   // of 16 m-tiles (o)
    const int wn = (wave >> 2) * 4;  // of 8 n-tiles (bn)

    const int ar = t >> 1, ah = t & 1;   // A staging: row, 16-float half
    const int br = t >> 2, bc = t & 3;   // B staging: row, 8-float chunk
    const float* Wrow = W + (size_t)(head * 256 + ar) * 256 + ah * 16;
    const float* hrow = hin + (size_t)(bn0 + br) * 256 + bc * 8;

    float4 pa0, pa1, pa2, pa3, pb0, pb1;
    {
        const float4* p4 = (const float4*)Wrow;
        pa0 = p4[0]; pa1 = p4[1]; pa2 = p4[2]; pa3 = p4[3];
        const float4* q4 = (const float4*)hrow;
        pb0 = q4[0]; pb1 = q4[1];
    }

    for (int f0 = 0; f0 < 256; f0 += 32) {
        __syncthreads();
        *(uint4*)((char*)As + swz(ar, 2 * ah)) =
            make_uint4(pack2(pa0.x, pa0.y), pack2(pa0.z, pa0.w),
                       pack2(pa1.x, pa1.y), pack2(pa1.z, pa1.w));
        *(uint4*)((char*)As + swz(ar, 2 * ah + 1)) =
            make_uint4(pack2(pa2.x, pa2.y), pack2(pa2.z, pa2.w),
                       pack2(pa3.x, pa3.y), pack2(pa3.z, pa3.w));
        *(uint4*)((char*)Bs + swz(br, bc)) =
            make_uint4(pack2(pb0.x, pb0.y), pack2(pb0.z, pb0.w),
                       pack2(pb1.x, pb1.y), pack2(pb1.z, pb1.w));
        if (f0 < 224) {   // prefetch next chunk (in flight across MFMA phase)
            const float4* p4 = (const float4*)(Wrow + f0 + 32);
            pa0 = p4[0]; pa1 = p4[1]; pa2 = p4[2]; pa3 = p4[3];
            const float4* q4 = (const float4*)(hrow + f0 + 32);
            pb0 = q4[0]; pb1 = q4[1];
        }
        __syncthreads();
        half8 af[4], bf[4];
#pragma unroll
        for (int a = 0; a < 4; a++)
            af[a] = *(const half8*)((char*)As + swz((wm + a) * 16 + l15, quad));
#pragma unroll
        for (int b = 0; b < 4; b++)
            bf[b] = *(const half8*)((char*)Bs + swz((wn + b) * 16 + l15, quad));
#pragma unroll
        for (int a = 0; a < 4; a++)
#pragma unroll
            for (int b = 0; b < 4; b++)
                acc[a][b] = __builtin_amdgcn_mfma_f32_16x16x32_f16(af[a], bf[b], acc[a][b], 0, 0, 0);
    }

    __syncthreads();   // tiles dead; overlay epilogue arrays
    if (t < 256) {
        bWs[t] = bW[head * 256 + t];
        a1s[t] = a1[head * 256 + t];
        a2s[t] = a2[head * 256 + t];
    }
    if (t < 128) { red1[t] = 0.f; red2[t] = 0.f; }
    __syncthreads();

    const int bidx = bn0 >> 10;
    const int nbase = bn0 & 1023;
#pragma unroll
    for (int b = 0; b < 4; b++) {
        const int bnl = (wn + b) * 16 + l15;     // local bn 0..127
        const int n = nbase + bnl;
        float p1 = 0.f, p2 = 0.f;
#pragma unroll
        for (int a = 0; a < 4; a++) {
#pragma unroll
            for (int r = 0; r < 4; r++) {
                int o = (wm + a) * 16 + quad * 4 + r;
                float v = acc[a][b][r] + bWs[o];
                WhT[(((size_t)(bidx * 8 + head) * 256 + o) << 10) + n] = (_Float16)v;
                p1 = fmaf(v, a1s[o], p1);
                p2 = fmaf(v, a2s[o], p2);
            }
        }
        atomicAdd(&red1[bnl], p1);
        atomicAdd(&red2[bnl], p2);
    }
    __syncthreads();
    if (t < 128) {
        const size_t idx = (size_t)(bidx * 8 + head) * 1024 + nbase + t;
        ei[idx] = red1[t];
        ej[idx] = red2[t];
    }
}

// ---------------------------------------------------------------------------
// Stage 2: out[b,i,h*256+o] = sigmoid(relu( (1/l_i) * sum_j p~_ij * Wh[j,o] ))
// p~ = exp2(lrelu((ci+ej))*L2E - m*L2E), l_i = sum_j p~ via MFMA vs ones.
// Tile 128(i) x 256(o), K=1024 in BK=32, 512 thr. Grid x=bh -> XCD locality.
__global__ __launch_bounds__(512, 4) void pv_kernel(
    const _Float16* __restrict__ WhT, const float* __restrict__ ei,
    const float* __restrict__ ej, const float* __restrict__ bA,
    float* __restrict__ out)
{
    const int bh = blockIdx.x;   // 0..127 (fast dim -> XCD key)
    const int it = blockIdx.y;   // 0..7
    const int b = bh >> 3, head = bh & 7;
    const int t = threadIdx.x;
    const int wave = t >> 6, lane = t & 63;
    const int l15 = lane & 15, quad = lane >> 4;

    __shared__ char smem[29248];
    _Float16* Ap = (_Float16*)smem;             // P tile 128 x 64B = 8192
    _Float16* Bp = (_Float16*)(smem + 8192);    // WhT tile 256 x 64B = 16384
    float* ejs  = (float*)(smem + 24576);       // 1024 f32 (pre-scaled *L2E)
    float* lns  = (float*)(smem + 28672);       // 128 row denominators
    float* wred = (float*)(smem + 29184);       // 8 per-wave maxes

    // preamble: stage ej*L2E, block-max
    const float* ejrow = ej + bh * 1024;
    float v0 = ejrow[t] * L2E, v1 = ejrow[t + 512] * L2E;
    ejs[t] = v0; ejs[t + 512] = v1;
    float mx = fmaxf(v0, v1);
#pragma unroll
    for (int m = 32; m; m >>= 1) mx = fmaxf(mx, __shfl_xor(mx, m, 64));
    if (lane == 0) wred[wave] = mx;
    __syncthreads();
    float ejmax = wred[0];
#pragma unroll
    for (int w = 1; w < 8; w++) ejmax = fmaxf(ejmax, wred[w]);

    const int i0 = it * 128;
    const int prow = t >> 2, pc = t & 3;   // P-gen: row, 8-elem chunk
    const float cip = (ei[bh * 1024 + i0 + prow] + bA[head]) * L2E;
    const float tmv = cip + ejmax;
    const float nm = -fmaxf(tmv, 0.2f * tmv);   // -m*log2e (exact row max)

    const int wr = t >> 1, wh2 = t & 1;    // B staging: row(o), 16-f16 half
    const _Float16* wrow = WhT + ((size_t)bh << 18) + ((size_t)wr << 10) + wh2 * 16;

    floatx4 acc[2][8], accl[2];
#pragma unroll
    for (int a = 0; a < 2; a++) {
        accl[a] = (floatx4)0.0f;
#pragma unroll
        for (int c = 0; c < 8; c++) acc[a][c] = (floatx4)0.0f;
    }
    const int wm = (wave >> 1) * 2;   // of 8 m-tiles (i)
    const int wn = (wave & 1) * 8;    // of 16 n-tiles (o)
    const bool doL = (wn == 0);
    const half8 ones = {1, 1, 1, 1, 1, 1, 1, 1};

    uint4 w0, w1;
    { const uint4* s = (const uint4*)wrow; w0 = s[0]; w1 = s[1]; }

    for (int j0 = 0; j0 < 1024; j0 += 32) {
        __syncthreads();
        {   // P-gen into Ap (all math in exp2 domain; lrelu is +homogeneous)
            const float* ejp = ejs + j0 + pc * 8;
            float p[8];
#pragma unroll
            for (int u = 0; u < 8; u++) {
                float e = cip + ejp[u];
                float lr = fmaxf(e, 0.2f * e);
                p[u] = EXP2F(lr + nm);
            }
            *(uint4*)((char*)Ap + swz(prow, pc)) =
                make_uint4(pack2(p[0], p[1]), pack2(p[2], p[3]),
                           pack2(p[4], p[5]), pack2(p[6], p[7]));
        }
        *(uint4*)((char*)Bp + swz(wr, 2 * wh2)) = w0;
        *(uint4*)((char*)Bp + swz(wr, 2 * wh2 + 1)) = w1;
        if (j0 < 992) {   // prefetch next WhT chunk
            const uint4* s = (const uint4*)(wrow + j0 + 32);
            w0 = s[0]; w1 = s[1];
        }
        __syncthreads();
        half8 af[2], bf[8];
#pragma unroll
        for (int a = 0; a < 2; a++)
            af[a] = *(const half8*)((char*)Ap + swz((wm + a) * 16 + l15, quad));
#pragma unroll
        for (int c = 0; c < 8; c++)
            bf[c] = *(const half8*)((char*)Bp + swz((wn + c) * 16 + l15, quad));
        if (doL) {
#pragma unroll
            for (int a = 0; a < 2; a++)
                accl[a] = __builtin_amdgcn_mfma_f32_16x16x32_f16(af[a], ones, accl[a], 0, 0, 0);
        }
#pragma unroll
        for (int a = 0; a < 2; a++)
#pragma unroll
            for (int c = 0; c < 8; c++)
                acc[a][c] = __builtin_amdgcn_mfma_f32_16x16x32_f16(af[a], bf[c], acc[a][c], 0, 0, 0);
    }

    __syncthreads();
    if (doL && l15 == 0) {   // all 16 cols identical; publish row sums
#pragma unroll
        for (int a = 0; a < 2; a++)
#pragma unroll
            for (int r = 0; r < 4; r++)
                lns[(wm + a) * 16 + quad * 4 + r] = accl[a][r];
    }
    __syncthreads();

    float rinv[2][4];
#pragma unroll
    for (int a = 0; a < 2; a++)
#pragma unroll
        for (int r = 0; r < 4; r++)
            rinv[a][r] = 1.0f / lns[(wm + a) * 16 + quad * 4 + r];   // l >= 1

#pragma unroll
    for (int a = 0; a < 2; a++) {
#pragma unroll
        for (int c = 0; c < 8; c++) {
            int o = (wn + c) * 16 + l15;
#pragma unroll
            for (int r = 0; r < 4; r++) {
                int i = i0 + (wm + a) * 16 + quad * 4 + r;
                float v = acc[a][c][r] * rinv[a][r];
                float rl = fmaxf(v, 0.0f);
                float y = 1.0f / (1.0f + EXP2F(-rl * L2E));
                out[((size_t)(b * 1024 + i) << 11) + head * 256 + o] = y;
            }
        }
    }
}

// ---------------------------------------------------------------------------
extern "C" void kernel_launch(void* const* d_in, const int* in_sizes, int n_in,
                              void* d_out, int out_size, void* d_ws, size_t ws_size,
                              hipStream_t stream)
{
    const float* h  = (const float*)d_in[0];
    const float* W  = (const float*)d_in[1];
    const float* bW = (const float*)d_in[2];
    const float* a1 = (const float*)d_in[3];
    const float* a2 = (const float*)d_in[4];
    const float* bA = (const float*)d_in[5];
    float* out = (float*)d_out;

    char* ws = (char*)d_ws;
    _Float16* WhT = (_Float16*)ws;                       // 67108864 B
    float* ei = (float*)(ws + 67108864);
    float* ej = (float*)(ws + 67108864 + 524288);

    hipLaunchKernelGGL(wh_kernel, dim3(128, 8), dim3(512), 0, stream,
                       h, W, bW, WhT, a1, a2, ei, ej);
    hipLaunchKernelGGL(pv_kernel, dim3(128, 8), dim3(512), 0, stream,
                       WhT, ei, ej, bA, out);
}

// Round 5
// 329.014 us; speedup vs baseline: 1.6790x; 1.6790x over previous
//
#include <hip/hip_runtime.h>

// GAT fused pipeline, fp16 MFMA (16x16x32), MI355X gfx950.
// B=16, N=1024, F_in=F_out=256, H=8, ALPHA=0.2
//
// Round-5: revert launch_bounds (512,4)->(512,2). Round-4's 2nd arg capped
// unified VGPR+AGPR at 128/wave -> accumulator spill -> 548MB scratch writes
// in pv. (512,2) caps at 256 regs: no spill (pv ~180, wh ~164 regs).
// Keep: swizzled zero-conflict LDS, register prefetch, fused ei/ej in wh,
// softmax denom via ones-MFMA in pv (no ml kernel).
//
// ws layout: [0,64MB) WhT fp16 [B][H][F_out][N]; +67108864 ei f32; +524288 ej f32.

#define L2E 1.442695041f

typedef _Float16 half8 __attribute__((ext_vector_type(8)));
typedef __fp16 fp16x2 __attribute__((ext_vector_type(2)));
typedef float floatx4 __attribute__((ext_vector_type(4)));

#if __has_builtin(__builtin_amdgcn_exp2f)
#define EXP2F(x) __builtin_amdgcn_exp2f(x)
#else
#define EXP2F(x) exp2f(x)
#endif

static __device__ inline unsigned int pack2(float a, float b) {
    fp16x2 h = __builtin_amdgcn_cvt_pkrtz(a, b);
    return __builtin_bit_cast(unsigned int, h);
}

// swizzled LDS byte address: [row][chunk c of 16B], 64B rows (no pad),
// c' = c ^ ((row>>1)&3). Uniform bank use for staging writes and b128 reads.
static __device__ inline int swz(int row, int c) {
    return (row << 6) + ((((c) ^ (row >> 1)) & 3) << 4);
}

// ---------------------------------------------------------------------------
// Stage 1: WhT[b,h,o,n] = sum_f W[h,o,f]*h[b,n,f] + bW[h,o]  (fp16 out)
// + fused ei/ej epilogue. Tile 256(o) x 128(bn), K=256, BK=32, 512 thr.
__global__ __launch_bounds__(512, 2) void wh_kernel(
    const float* __restrict__ hin, const float* __restrict__ W,
    const float* __restrict__ bW, _Float16* __restrict__ WhT,
    const float* __restrict__ a1, const float* __restrict__ a2,
    float* __restrict__ ei, float* __restrict__ ej)
{
    const int bnt  = blockIdx.x;   // 0..127
    const int head = blockIdx.y;   // 0..7
    const int t    = threadIdx.x;
    const int wave = t >> 6, lane = t & 63;
    const int l15 = lane & 15, quad = lane >> 4;

    __shared__ char smem[24576];
    _Float16* As = (_Float16*)smem;            // 256 rows x 64B = 16384
    _Float16* Bs = (_Float16*)(smem + 16384);  // 128 rows x 64B = 8192
    // epilogue overlay on As region (dead after K-loop):
    float* bWs  = (float*)smem;
    float* a1s  = (float*)(smem + 1024);
    float* a2s  = (float*)(smem + 2048);
    float* red1 = (float*)(smem + 3072);
    float* red2 = (float*)(smem + 3584);

    const int bn0 = bnt * 128;
    floatx4 acc[4][4];
#pragma unroll
    for (int a = 0; a < 4; a++)
#pragma unroll
        for (int b = 0; b < 4; b++) acc[a][b] = (floatx4)0.0f;

    const int wm = (wave & 3) * 4;   // of 16 m-tiles (o)
    const int wn = (wave >> 2) * 4;  // of 8 n-tiles (bn)

    const int ar = t >> 1, ah = t & 1;   // A staging: row, 16-float half
    const int br = t >> 2, bc = t & 3;   // B staging: row, 8-float chunk
    const float* Wrow = W + (size_t)(head * 256 + ar) * 256 + ah * 16;
    const float* hrow = hin + (size_t)(bn0 + br) * 256 + bc * 8;

    float4 pa0, pa1, pa2, pa3, pb0, pb1;
    {
        const float4* p4 = (const float4*)Wrow;
        pa0 = p4[0]; pa1 = p4[1]; pa2 = p4[2]; pa3 = p4[3];
        const float4* q4 = (const float4*)hrow;
        pb0 = q4[0]; pb1 = q4[1];
    }

    for (int f0 = 0; f0 < 256; f0 += 32) {
        __syncthreads();
        *(uint4*)((char*)As + swz(ar, 2 * ah)) =
            make_uint4(pack2(pa0.x, pa0.y), pack2(pa0.z, pa0.w),
                       pack2(pa1.x, pa1.y), pack2(pa1.z, pa1.w));
        *(uint4*)((char*)As + swz(ar, 2 * ah + 1)) =
            make_uint4(pack2(pa2.x, pa2.y), pack2(pa2.z, pa2.w),
                       pack2(pa3.x, pa3.y), pack2(pa3.z, pa3.w));
        *(uint4*)((char*)Bs + swz(br, bc)) =
            make_uint4(pack2(pb0.x, pb0.y), pack2(pb0.z, pb0.w),
                       pack2(pb1.x, pb1.y), pack2(pb1.z, pb1.w));
        if (f0 < 224) {   // prefetch next chunk (in flight across MFMA phase)
            const float4* p4 = (const float4*)(Wrow + f0 + 32);
            pa0 = p4[0]; pa1 = p4[1]; pa2 = p4[2]; pa3 = p4[3];
            const float4* q4 = (const float4*)(hrow + f0 + 32);
            pb0 = q4[0]; pb1 = q4[1];
        }
        __syncthreads();
        half8 af[4], bf[4];
#pragma unroll
        for (int a = 0; a < 4; a++)
            af[a] = *(const half8*)((char*)As + swz((wm + a) * 16 + l15, quad));
#pragma unroll
        for (int b = 0; b < 4; b++)
            bf[b] = *(const half8*)((char*)Bs + swz((wn + b) * 16 + l15, quad));
#pragma unroll
        for (int a = 0; a < 4; a++)
#pragma unroll
            for (int b = 0; b < 4; b++)
                acc[a][b] = __builtin_amdgcn_mfma_f32_16x16x32_f16(af[a], bf[b], acc[a][b], 0, 0, 0);
    }

    __syncthreads();   // tiles dead; overlay epilogue arrays
    if (t < 256) {
        bWs[t] = bW[head * 256 + t];
        a1s[t] = a1[head * 256 + t];
        a2s[t] = a2[head * 256 + t];
    }
    if (t < 128) { red1[t] = 0.f; red2[t] = 0.f; }
    __syncthreads();

    const int bidx = bn0 >> 10;
    const int nbase = bn0 & 1023;
#pragma unroll
    for (int b = 0; b < 4; b++) {
        const int bnl = (wn + b) * 16 + l15;     // local bn 0..127
        const int n = nbase + bnl;
        float p1 = 0.f, p2 = 0.f;
#pragma unroll
        for (int a = 0; a < 4; a++) {
#pragma unroll
            for (int r = 0; r < 4; r++) {
                int o = (wm + a) * 16 + quad * 4 + r;
                float v = acc[a][b][r] + bWs[o];
                WhT[(((size_t)(bidx * 8 + head) * 256 + o) << 10) + n] = (_Float16)v;
                p1 = fmaf(v, a1s[o], p1);
                p2 = fmaf(v, a2s[o], p2);
            }
        }
        atomicAdd(&red1[bnl], p1);
        atomicAdd(&red2[bnl], p2);
    }
    __syncthreads();
    if (t < 128) {
        const size_t idx = (size_t)(bidx * 8 + head) * 1024 + nbase + t;
        ei[idx] = red1[t];
        ej[idx] = red2[t];
    }
}

// ---------------------------------------------------------------------------
// Stage 2: out[b,i,h*256+o] = sigmoid(relu( (1/l_i) * sum_j p~_ij * Wh[j,o] ))
// p~ = exp2(lrelu(ci+ej)*L2E - m*L2E), l_i = sum_j p~ via MFMA vs ones.
// Tile 128(i) x 256(o), K=1024 in BK=32, 512 thr. Grid x=bh -> XCD locality.
__global__ __launch_bounds__(512, 2) void pv_kernel(
    const _Float16* __restrict__ WhT, const float* __restrict__ ei,
    const float* __restrict__ ej, const float* __restrict__ bA,
    float* __restrict__ out)
{
    const int bh = blockIdx.x;   // 0..127 (fast dim -> XCD key)
    const int it = blockIdx.y;   // 0..7
    const int b = bh >> 3, head = bh & 7;
    const int t = threadIdx.x;
    const int wave = t >> 6, lane = t & 63;
    const int l15 = lane & 15, quad = lane >> 4;

    __shared__ char smem[29248];
    _Float16* Ap = (_Float16*)smem;             // P tile 128 x 64B = 8192
    _Float16* Bp = (_Float16*)(smem + 8192);    // WhT tile 256 x 64B = 16384
    float* ejs  = (float*)(smem + 24576);       // 1024 f32 (pre-scaled *L2E)
    float* lns  = (float*)(smem + 28672);       // 128 row denominators
    float* wred = (float*)(smem + 29184);       // 8 per-wave maxes

    // preamble: stage ej*L2E, block-max
    const float* ejrow = ej + bh * 1024;
    float v0 = ejrow[t] * L2E, v1 = ejrow[t + 512] * L2E;
    ejs[t] = v0; ejs[t + 512] = v1;
    float mx = fmaxf(v0, v1);
#pragma unroll
    for (int m = 32; m; m >>= 1) mx = fmaxf(mx, __shfl_xor(mx, m, 64));
    if (lane == 0) wred[wave] = mx;
    __syncthreads();
    float ejmax = wred[0];
#pragma unroll
    for (int w = 1; w < 8; w++) ejmax = fmaxf(ejmax, wred[w]);

    const int i0 = it * 128;
    const int prow = t >> 2, pc = t & 3;   // P-gen: row, 8-elem chunk
    const float cip = (ei[bh * 1024 + i0 + prow] + bA[head]) * L2E;
    const float tmv = cip + ejmax;
    const float nm = -fmaxf(tmv, 0.2f * tmv);   // -m*log2e (exact row max)

    const int wr = t >> 1, wh2 = t & 1;    // B staging: row(o), 16-f16 half
    const _Float16* wrow = WhT + ((size_t)bh << 18) + ((size_t)wr << 10) + wh2 * 16;

    floatx4 acc[2][8], accl[2];
#pragma unroll
    for (int a = 0; a < 2; a++) {
        accl[a] = (floatx4)0.0f;
#pragma unroll
        for (int c = 0; c < 8; c++) acc[a][c] = (floatx4)0.0f;
    }
    const int wm = (wave >> 1) * 2;   // of 8 m-tiles (i)
    const int wn = (wave & 1) * 8;    // of 16 n-tiles (o)
    const bool doL = (wn == 0);
    const half8 ones = {1, 1, 1, 1, 1, 1, 1, 1};

    uint4 w0, w1;
    { const uint4* s = (const uint4*)wrow; w0 = s[0]; w1 = s[1]; }

    for (int j0 = 0; j0 < 1024; j0 += 32) {
        __syncthreads();
        {   // P-gen into Ap (exp2 domain; lrelu commutes with +scale)
            const float* ejp = ejs + j0 + pc * 8;
            float p[8];
#pragma unroll
            for (int u = 0; u < 8; u++) {
                float e = cip + ejp[u];
                float lr = fmaxf(e, 0.2f * e);
                p[u] = EXP2F(lr + nm);
            }
            *(uint4*)((char*)Ap + swz(prow, pc)) =
                make_uint4(pack2(p[0], p[1]), pack2(p[2], p[3]),
                           pack2(p[4], p[5]), pack2(p[6], p[7]));
        }
        *(uint4*)((char*)Bp + swz(wr, 2 * wh2)) = w0;
        *(uint4*)((char*)Bp + swz(wr, 2 * wh2 + 1)) = w1;
        if (j0 < 992) {   // prefetch next WhT chunk
            const uint4* s = (const uint4*)(wrow + j0 + 32);
            w0 = s[0]; w1 = s[1];
        }
        __syncthreads();
        half8 af[2], bf[8];
#pragma unroll
        for (int a = 0; a < 2; a++)
            af[a] = *(const half8*)((char*)Ap + swz((wm + a) * 16 + l15, quad));
#pragma unroll
        for (int c = 0; c < 8; c++)
            bf[c] = *(const half8*)((char*)Bp + swz((wn + c) * 16 + l15, quad));
        if (doL) {
#pragma unroll
            for (int a = 0; a < 2; a++)
                accl[a] = __builtin_amdgcn_mfma_f32_16x16x32_f16(af[a], ones, accl[a], 0, 0, 0);
        }
#pragma unroll
        for (int a = 0; a < 2; a++)
#pragma unroll
            for (int c = 0; c < 8; c++)
                acc[a][c] = __builtin_amdgcn_mfma_f32_16x16x32_f16(af[a], bf[c], acc[a][c], 0, 0, 0);
    }

    __syncthreads();
    if (doL && l15 == 0) {   // all 16 cols identical; publish row sums
#pragma unroll
        for (int a = 0; a < 2; a++)
#pragma unroll
            for (int r = 0; r < 4; r++)
                lns[(wm + a) * 16 + quad * 4 + r] = accl[a][r];
    }
    __syncthreads();

    float rinv[2][4];
#pragma unroll
    for (int a = 0; a < 2; a++)
#pragma unroll
        for (int r = 0; r < 4; r++)
            rinv[a][r] = 1.0f / lns[(wm + a) * 16 + quad * 4 + r];   // l >= 1

#pragma unroll
    for (int a = 0; a < 2; a++) {
#pragma unroll
        for (int c = 0; c < 8; c++) {
            int o = (wn + c) * 16 + l15;
#pragma unroll
            for (int r = 0; r < 4; r++) {
                int i = i0 + (wm + a) * 16 + quad * 4 + r;
                float v = acc[a][c][r] * rinv[a][r];
                float rl = fmaxf(v, 0.0f);
                float y = 1.0f / (1.0f + EXP2F(-rl * L2E));
                out[((size_t)(b * 1024 + i) << 11) + head * 256 + o] = y;
            }
        }
    }
}

// ---------------------------------------------------------------------------
extern "C" void kernel_launch(void* const* d_in, const int* in_sizes, int n_in,
                              void* d_out, int out_size, void* d_ws, size_t ws_size,
                              hipStream_t stream)
{
    const float* h  = (const float*)d_in[0];
    const float* W  = (const float*)d_in[1];
    const float* bW = (const float*)d_in[2];
    const float* a1 = (const float*)d_in[3];
    const float* a2 = (const float*)d_in[4];
    const float* bA = (const float*)d_in[5];
    float* out = (float*)d_out;

    char* ws = (char*)d_ws;
    _Float16* WhT = (_Float16*)ws;                       // 67108864 B
    float* ei = (float*)(ws + 67108864);
    float* ej = (float*)(ws + 67108864 + 524288);

    hipLaunchKernelGGL(wh_kernel, dim3(128, 8), dim3(512), 0, stream,
                       h, W, bW, WhT, a1, a2, ei, ej);
    hipLaunchKernelGGL(pv_kernel, dim3(128, 8), dim3(512), 0, stream,
                       WhT, ei, ej, bA, out);
}

// Round 6
// 321.985 us; speedup vs baseline: 1.7156x; 1.0218x over previous
//
#include <hip/hip_runtime.h>

// GAT fused pipeline, fp16 MFMA (16x16x32), MI355X gfx950.
// B=16, N=1024, F_in=F_out=256, H=8, ALPHA=0.2
//
// Round-6:
//  - wh: REMOVE LDS atomicAdd reduction (4096 atomics -> 128 addrs was the
//    suspected serialization killer). Now shfl_xor quad-reduce + plain LDS
//    partials + 128-thread sum.
//  - pv: BK 32->64 (half the barriers), wave tile 64x64 (4m x 4n of 16) ->
//    frag LDS reads -20%; 128B LDS rows with XOR-chunk swizzle (conflict-free
//    for staging writes and b128 frag reads); LDS ~54KB -> 2 blocks/CU.
//
// ws layout: [0,64MB) WhT fp16 [B][H][F_out][N]; +67108864 ei f32; +524288 ej f32.

#define L2E 1.442695041f

typedef _Float16 half8 __attribute__((ext_vector_type(8)));
typedef __fp16 fp16x2 __attribute__((ext_vector_type(2)));
typedef float floatx4 __attribute__((ext_vector_type(4)));

#if __has_builtin(__builtin_amdgcn_exp2f)
#define EXP2F(x) __builtin_amdgcn_exp2f(x)
#else
#define EXP2F(x) exp2f(x)
#endif

static __device__ inline unsigned int pack2(float a, float b) {
    fp16x2 h = __builtin_amdgcn_cvt_pkrtz(a, b);
    return __builtin_bit_cast(unsigned int, h);
}

// 64B-row swizzle (wh tiles): chunk c of 16B, c' = c ^ ((row>>1)&3)
static __device__ inline int swz(int row, int c) {
    return (row << 6) + ((((c) ^ (row >> 1)) & 3) << 4);
}
// 128B-row swizzle (pv tiles): 8 chunks of 16B, c' = c ^ (row&7)
static __device__ inline int swz128(int row, int c) {
    return (row << 7) + ((((c) ^ row) & 7) << 4);
}

// ---------------------------------------------------------------------------
// Stage 1: WhT[b,h,o,n] = sum_f W[h,o,f]*h[b,n,f] + bW[h,o]  (fp16 out)
// + fused ei/ej epilogue (atomic-free). 256(o) x 128(bn), K=256, BK=32.
__global__ __launch_bounds__(512, 2) void wh_kernel(
    const float* __restrict__ hin, const float* __restrict__ W,
    const float* __restrict__ bW, _Float16* __restrict__ WhT,
    const float* __restrict__ a1, const float* __restrict__ a2,
    float* __restrict__ ei, float* __restrict__ ej)
{
    const int bnt  = blockIdx.x;   // 0..127
    const int head = blockIdx.y;   // 0..7
    const int t    = threadIdx.x;
    const int wave = t >> 6, lane = t & 63;
    const int l15 = lane & 15, quad = lane >> 4;

    __shared__ char smem[24576];
    _Float16* As = (_Float16*)smem;            // 256 rows x 64B = 16384
    _Float16* Bs = (_Float16*)(smem + 16384);  // 128 rows x 64B = 8192
    // epilogue overlay (tiles dead after K-loop):
    float* bWs   = (float*)smem;               // 256 f32
    float* a1s   = (float*)(smem + 1024);
    float* a2s   = (float*)(smem + 2048);
    float* part1 = (float*)(smem + 3072);      // [2 g][4 wmw][64 row] = 2KB
    float* part2 = (float*)(smem + 5120);      // 2KB

    const int bn0 = bnt * 128;
    floatx4 acc[4][4];
#pragma unroll
    for (int a = 0; a < 4; a++)
#pragma unroll
        for (int b = 0; b < 4; b++) acc[a][b] = (floatx4)0.0f;

    const int wm = (wave & 3) * 4;   // of 16 m-tiles (o)
    const int wn = (wave >> 2) * 4;  // of 8 n-tiles (bn)

    const int ar = t >> 1, ah = t & 1;   // A staging: row, 16-float half
    const int br = t >> 2, bc = t & 3;   // B staging: row, 8-float chunk
    const float* Wrow = W + (size_t)(head * 256 + ar) * 256 + ah * 16;
    const float* hrow = hin + (size_t)(bn0 + br) * 256 + bc * 8;

    float4 pa0, pa1, pa2, pa3, pb0, pb1;
    {
        const float4* p4 = (const float4*)Wrow;
        pa0 = p4[0]; pa1 = p4[1]; pa2 = p4[2]; pa3 = p4[3];
        const float4* q4 = (const float4*)hrow;
        pb0 = q4[0]; pb1 = q4[1];
    }

    for (int f0 = 0; f0 < 256; f0 += 32) {
        __syncthreads();
        *(uint4*)((char*)As + swz(ar, 2 * ah)) =
            make_uint4(pack2(pa0.x, pa0.y), pack2(pa0.z, pa0.w),
                       pack2(pa1.x, pa1.y), pack2(pa1.z, pa1.w));
        *(uint4*)((char*)As + swz(ar, 2 * ah + 1)) =
            make_uint4(pack2(pa2.x, pa2.y), pack2(pa2.z, pa2.w),
                       pack2(pa3.x, pa3.y), pack2(pa3.z, pa3.w));
        *(uint4*)((char*)Bs + swz(br, bc)) =
            make_uint4(pack2(pb0.x, pb0.y), pack2(pb0.z, pb0.w),
                       pack2(pb1.x, pb1.y), pack2(pb1.z, pb1.w));
        if (f0 < 224) {   // prefetch next chunk
            const float4* p4 = (const float4*)(Wrow + f0 + 32);
            pa0 = p4[0]; pa1 = p4[1]; pa2 = p4[2]; pa3 = p4[3];
            const float4* q4 = (const float4*)(hrow + f0 + 32);
            pb0 = q4[0]; pb1 = q4[1];
        }
        __syncthreads();
        half8 af[4], bf[4];
#pragma unroll
        for (int a = 0; a < 4; a++)
            af[a] = *(const half8*)((char*)As + swz((wm + a) * 16 + l15, quad));
#pragma unroll
        for (int b = 0; b < 4; b++)
            bf[b] = *(const half8*)((char*)Bs + swz((wn + b) * 16 + l15, quad));
#pragma unroll
        for (int a = 0; a < 4; a++)
#pragma unroll
            for (int b = 0; b < 4; b++)
                acc[a][b] = __builtin_amdgcn_mfma_f32_16x16x32_f16(af[a], bf[b], acc[a][b], 0, 0, 0);
    }

    __syncthreads();   // tiles dead; overlay epilogue arrays
    if (t < 256) {
        bWs[t] = bW[head * 256 + t];
        a1s[t] = a1[head * 256 + t];
        a2s[t] = a2[head * 256 + t];
    }
    __syncthreads();

    const int bidx = bn0 >> 10;
    const int nbase = bn0 & 1023;
    const int g = wave >> 2;         // wn group (rows 0..63 / 64..127)
    const int wmw = wave & 3;        // wm-wave index within group
#pragma unroll
    for (int b = 0; b < 4; b++) {
        const int bnl = (wn + b) * 16 + l15;     // local bn 0..127
        const int n = nbase + bnl;
        float p1 = 0.f, p2 = 0.f;
#pragma unroll
        for (int a = 0; a < 4; a++) {
#pragma unroll
            for (int r = 0; r < 4; r++) {
                int o = (wm + a) * 16 + quad * 4 + r;
                float v = acc[a][b][r] + bWs[o];
                WhT[(((size_t)(bidx * 8 + head) * 256 + o) << 10) + n] = (_Float16)v;
                p1 = fmaf(v, a1s[o], p1);
                p2 = fmaf(v, a2s[o], p2);
            }
        }
        // quad-reduce within wave (rows indexed by l15; 4 quads contribute)
        p1 += __shfl_xor(p1, 16, 64); p1 += __shfl_xor(p1, 32, 64);
        p2 += __shfl_xor(p2, 16, 64); p2 += __shfl_xor(p2, 32, 64);
        if (lane < 16) {
            part1[g * 256 + wmw * 64 + b * 16 + lane] = p1;
            part2[g * 256 + wmw * 64 + b * 16 + lane] = p2;
        }
    }
    __syncthreads();
    if (t < 128) {
        const int gg = t >> 6, r = t & 63;
        float s1 = 0.f, s2 = 0.f;
#pragma unroll
        for (int w = 0; w < 4; w++) {
            s1 += part1[gg * 256 + w * 64 + r];
            s2 += part2[gg * 256 + w * 64 + r];
        }
        const size_t idx = (size_t)(bidx * 8 + head) * 1024 + nbase + t;
        ei[idx] = s1;
        ej[idx] = s2;
    }
}

// ---------------------------------------------------------------------------
// Stage 2: out[b,i,h*256+o] = sigmoid(relu( (1/l_i) * sum_j p~_ij * Wh[j,o] ))
// p~ = exp2(lrelu(ci+ej)*L2E - m*L2E), l_i via MFMA vs ones.
// Tile 128(i) x 256(o), K=1024 in BK=64, 512 thr, wave tile 64x64.
__global__ __launch_bounds__(512, 2) void pv_kernel(
    const _Float16* __restrict__ WhT, const float* __restrict__ ei,
    const float* __restrict__ ej, const float* __restrict__ bA,
    float* __restrict__ out)
{
    const int bh = blockIdx.x;   // 0..127 (fast dim -> XCD key)
    const int it = blockIdx.y;   // 0..7
    const int b = bh >> 3, head = bh & 7;
    const int t = threadIdx.x;
    const int wave = t >> 6, lane = t & 63;
    const int l15 = lane & 15, quad = lane >> 4;

    __shared__ char smem[53824];
    _Float16* Ap = (_Float16*)smem;             // P: 128 rows x 128B = 16384
    _Float16* Bp = (_Float16*)(smem + 16384);   // WhT: 256 rows x 128B = 32768
    float* ejs  = (float*)(smem + 49152);       // 1024 f32 (*L2E)  4KB
    float* lns  = (float*)(smem + 53248);       // 128 denominators
    float* wred = (float*)(smem + 53760);       // 8 wave maxes

    // preamble: stage ej*L2E, block-max
    const float* ejrow = ej + bh * 1024;
    float v0 = ejrow[t] * L2E, v1 = ejrow[t + 512] * L2E;
    ejs[t] = v0; ejs[t + 512] = v1;
    float mx = fmaxf(v0, v1);
#pragma unroll
    for (int m = 32; m; m >>= 1) mx = fmaxf(mx, __shfl_xor(mx, m, 64));
    if (lane == 0) wred[wave] = mx;
    __syncthreads();
    float ejmax = wred[0];
#pragma unroll
    for (int w = 1; w < 8; w++) ejmax = fmaxf(ejmax, wred[w]);

    const int i0 = it * 128;
    const int prow = t >> 2, pjb = (t & 3) * 16;   // P-gen: row, 16-j chunk
    const float cip = (ei[bh * 1024 + i0 + prow] + bA[head]) * L2E;
    const float tmv = cip + ejmax;
    const float nm = -fmaxf(tmv, 0.2f * tmv);      // -m*log2e

    const int wr_ = t >> 1, hh = t & 1;   // B staging: row(o), 64B half
    const _Float16* wrow = WhT + ((size_t)bh << 18) + ((size_t)wr_ << 10) + hh * 32;

    floatx4 acc[4][4], accl[4];
#pragma unroll
    for (int a = 0; a < 4; a++) {
        accl[a] = (floatx4)0.0f;
#pragma unroll
        for (int c = 0; c < 4; c++) acc[a][c] = (floatx4)0.0f;
    }
    const int wm = (wave >> 2) * 4;   // of 8 m-tiles (i): groups of 4
    const int wn = (wave & 3) * 4;    // of 16 n-tiles (o): groups of 4
    const bool doL = ((wave & 3) == 0);
    const half8 ones = {1, 1, 1, 1, 1, 1, 1, 1};

    uint4 w0, w1, w2, w3;
    { const uint4* s = (const uint4*)wrow; w0 = s[0]; w1 = s[1]; w2 = s[2]; w3 = s[3]; }

    for (int j0 = 0; j0 < 1024; j0 += 64) {
        __syncthreads();
        {   // P-gen: 16 values -> two swizzled uint4 (chunks 2*(t&3), +1)
            const float* ejp = ejs + j0 + pjb;
            float p[16];
#pragma unroll
            for (int u = 0; u < 16; u++) {
                float e = cip + ejp[u];
                float lr = fmaxf(e, 0.2f * e);
                p[u] = EXP2F(lr + nm);
            }
            const int c0 = (t & 3) * 2;
            *(uint4*)((char*)Ap + swz128(prow, c0)) =
                make_uint4(pack2(p[0], p[1]), pack2(p[2], p[3]),
                           pack2(p[4], p[5]), pack2(p[6], p[7]));
            *(uint4*)((char*)Ap + swz128(prow, c0 + 1)) =
                make_uint4(pack2(p[8], p[9]), pack2(p[10], p[11]),
                           pack2(p[12], p[13]), pack2(p[14], p[15]));
        }
        {   // B staging: 64B (4 chunks at 4*hh..4*hh+3)
            const int c0 = 4 * hh;
            *(uint4*)((char*)Bp + swz128(wr_, c0))     = w0;
            *(uint4*)((char*)Bp + swz128(wr_, c0 + 1)) = w1;
            *(uint4*)((char*)Bp + swz128(wr_, c0 + 2)) = w2;
            *(uint4*)((char*)Bp + swz128(wr_, c0 + 3)) = w3;
        }
        if (j0 < 960) {   // prefetch next 64-j chunk
            const uint4* s = (const uint4*)(wrow + j0 + 64);
            w0 = s[0]; w1 = s[1]; w2 = s[2]; w3 = s[3];
        }
        __syncthreads();
#pragma unroll
        for (int kk = 0; kk < 2; kk++) {
            half8 af[4], bf[4];
#pragma unroll
            for (int a = 0; a < 4; a++)
                af[a] = *(const half8*)((char*)Ap + swz128((wm + a) * 16 + l15, kk * 4 + quad));
#pragma unroll
            for (int c = 0; c < 4; c++)
                bf[c] = *(const half8*)((char*)Bp + swz128((wn + c) * 16 + l15, kk * 4 + quad));
            if (doL) {
#pragma unroll
                for (int a = 0; a < 4; a++)
                    accl[a] = __builtin_amdgcn_mfma_f32_16x16x32_f16(af[a], ones, accl[a], 0, 0, 0);
            }
#pragma unroll
            for (int a = 0; a < 4; a++)
#pragma unroll
                for (int c = 0; c < 4; c++)
                    acc[a][c] = __builtin_amdgcn_mfma_f32_16x16x32_f16(af[a], bf[c], acc[a][c], 0, 0, 0);
        }
    }

    __syncthreads();
    if (doL && l15 == 0) {   // all 16 cols identical; publish row sums
#pragma unroll
        for (int a = 0; a < 4; a++)
#pragma unroll
            for (int r = 0; r < 4; r++)
                lns[(wm + a) * 16 + quad * 4 + r] = accl[a][r];
    }
    __syncthreads();

    float rinv[4][4];
#pragma unroll
    for (int a = 0; a < 4; a++)
#pragma unroll
        for (int r = 0; r < 4; r++)
            rinv[a][r] = 1.0f / lns[(wm + a) * 16 + quad * 4 + r];

#pragma unroll
    for (int a = 0; a < 4; a++) {
#pragma unroll
        for (int c = 0; c < 4; c++) {
            int o = (wn + c) * 16 + l15;
#pragma unroll
            for (int r = 0; r < 4; r++) {
                int i = i0 + (wm + a) * 16 + quad * 4 + r;
                float v = acc[a][c][r] * rinv[a][r];
                float rl = fmaxf(v, 0.0f);
                float y = 1.0f / (1.0f + EXP2F(-rl * L2E));
                out[((size_t)(b * 1024 + i) << 11) + head * 256 + o] = y;
            }
        }
    }
}

// ---------------------------------------------------------------------------
extern "C" void kernel_launch(void* const* d_in, const int* in_sizes, int n_in,
                              void* d_out, int out_size, void* d_ws, size_t ws_size,
                              hipStream_t stream)
{
    const float* h  = (const float*)d_in[0];
    const float* W  = (const float*)d_in[1];
    const float* bW = (const float*)d_in[2];
    const float* a1 = (const float*)d_in[3];
    const float* a2 = (const float*)d_in[4];
    const float* bA = (const float*)d_in[5];
    float* out = (float*)d_out;

    char* ws = (char*)d_ws;
    _Float16* WhT = (_Float16*)ws;                       // 67108864 B
    float* ei = (float*)(ws + 67108864);
    float* ej = (float*)(ws + 67108864 + 524288);

    hipLaunchKernelGGL(wh_kernel, dim3(128, 8), dim3(512), 0, stream,
                       h, W, bW, WhT, a1, a2, ei, ej);
    hipLaunchKernelGGL(pv_kernel, dim3(128, 8), dim3(512), 0, stream,
                       WhT, ei, ej, bA, out);
}

// Round 7
// 295.401 us; speedup vs baseline: 1.8700x; 1.0900x over previous
//
#include <hip/hip_runtime.h>

// GAT fused pipeline, fp16 MFMA (16x16x32), MI355X gfx950.
// B=16, N=1024, F_in=F_out=256, H=8, ALPHA=0.2
//
// Round-7: occupancy fix. 512-thr blocks at 164 unified regs = 1 block/CU
// (656 regs/EU needed for 2 > 512) -> every barrier idled the CU. Now
// 256-thr blocks, 128x128 tiles, launch_bounds(256,3): 3 blocks/CU
// co-resident, barriers overlap across blocks.
//  - wh: grid (128 bnt, 2 ot, 8 head); ei/ej partials per ot half summed
//    in pv preamble (atomic-free, no memset).
//  - pv: grid (128 bh, 8 it, 2 ot); P-gen duplicated per ot (cheap);
//    ej staged in LDS, read as broadcast float4 (row-independent addr).
//
// ws: [0,64MB) WhT fp16 [B][H][F_out][N]; +67108864 eiP[2][128K] f32;
//     +68157440 ejP[2][128K] f32. Total 66 MiB.

#define L2E 1.442695041f

typedef _Float16 half8 __attribute__((ext_vector_type(8)));
typedef __fp16 fp16x2 __attribute__((ext_vector_type(2)));
typedef float floatx4 __attribute__((ext_vector_type(4)));

#if __has_builtin(__builtin_amdgcn_exp2f)
#define EXP2F(x) __builtin_amdgcn_exp2f(x)
#else
#define EXP2F(x) exp2f(x)
#endif

static __device__ inline unsigned int pack2(float a, float b) {
    fp16x2 h = __builtin_amdgcn_cvt_pkrtz(a, b);
    return __builtin_bit_cast(unsigned int, h);
}

// 64B-row swizzle (wh tiles): chunk c of 16B, c' = c ^ ((row>>1)&3)
static __device__ inline int swz(int row, int c) {
    return (row << 6) + ((((c) ^ (row >> 1)) & 3) << 4);
}
// 128B-row swizzle (pv tiles): 8 chunks of 16B, c' = c ^ (row&7)
static __device__ inline int swz128(int row, int c) {
    return (row << 7) + ((((c) ^ row) & 7) << 4);
}

// ---------------------------------------------------------------------------
// Stage 1: WhT[b,h,o,n] = sum_f W[h,o,f]*h[b,n,f] + bW[h,o]  (fp16 out)
// + per-ot ei/ej partial epilogue. Tile 128(o) x 128(bn), K=256, BK=32.
// 256 thr = 4 waves (wmh = wave&1 over o, wnh = wave>>1 over bn), 4x4 tiles.
__global__ __launch_bounds__(256, 3) void wh_kernel(
    const float* __restrict__ hin, const float* __restrict__ W,
    const float* __restrict__ bW, _Float16* __restrict__ WhT,
    const float* __restrict__ a1, const float* __restrict__ a2,
    float* __restrict__ eiP, float* __restrict__ ejP)
{
    const int bnt  = blockIdx.x;   // 0..127
    const int ot   = blockIdx.y;   // 0..1
    const int head = blockIdx.z;   // 0..7
    const int t    = threadIdx.x;
    const int wave = t >> 6, lane = t & 63;
    const int l15 = lane & 15, quad = lane >> 4;
    const int wmh = wave & 1, wnh = wave >> 1;

    __shared__ char smem[16384];
    _Float16* As = (_Float16*)smem;            // 128 rows x 64B = 8192
    _Float16* Bs = (_Float16*)(smem + 8192);   // 128 rows x 64B = 8192
    // epilogue overlay (tiles dead after K-loop):
    float* bWs   = (float*)smem;               // 128 f32
    float* a1s   = (float*)(smem + 512);
    float* a2s   = (float*)(smem + 1024);
    float* part1 = (float*)(smem + 1536);      // [2 wmh][128 row] = 1KB
    float* part2 = (float*)(smem + 2560);      // 1KB

    const int o0 = ot * 128;
    const int bn0 = bnt * 128;
    floatx4 acc[4][4];
#pragma unroll
    for (int a = 0; a < 4; a++)
#pragma unroll
        for (int b = 0; b < 4; b++) acc[a][b] = (floatx4)0.0f;

    const int ar = t >> 1, ah = t & 1;   // staging: row, 16-float half
    const float* Wrow = W + (size_t)(head * 256 + o0 + ar) * 256 + ah * 16;
    const float* hrow = hin + (size_t)(bn0 + ar) * 256 + ah * 16;

    float4 pa0, pa1, pa2, pa3, pb0, pb1, pb2, pb3;
    {
        const float4* p4 = (const float4*)Wrow;
        pa0 = p4[0]; pa1 = p4[1]; pa2 = p4[2]; pa3 = p4[3];
        const float4* q4 = (const float4*)hrow;
        pb0 = q4[0]; pb1 = q4[1]; pb2 = q4[2]; pb3 = q4[3];
    }

    for (int f0 = 0; f0 < 256; f0 += 32) {
        __syncthreads();
        *(uint4*)((char*)As + swz(ar, 2 * ah)) =
            make_uint4(pack2(pa0.x, pa0.y), pack2(pa0.z, pa0.w),
                       pack2(pa1.x, pa1.y), pack2(pa1.z, pa1.w));
        *(uint4*)((char*)As + swz(ar, 2 * ah + 1)) =
            make_uint4(pack2(pa2.x, pa2.y), pack2(pa2.z, pa2.w),
                       pack2(pa3.x, pa3.y), pack2(pa3.z, pa3.w));
        *(uint4*)((char*)Bs + swz(ar, 2 * ah)) =
            make_uint4(pack2(pb0.x, pb0.y), pack2(pb0.z, pb0.w),
                       pack2(pb1.x, pb1.y), pack2(pb1.z, pb1.w));
        *(uint4*)((char*)Bs + swz(ar, 2 * ah + 1)) =
            make_uint4(pack2(pb2.x, pb2.y), pack2(pb2.z, pb2.w),
                       pack2(pb3.x, pb3.y), pack2(pb3.z, pb3.w));
        if (f0 < 224) {   // prefetch next chunk
            const float4* p4 = (const float4*)(Wrow + f0 + 32);
            pa0 = p4[0]; pa1 = p4[1]; pa2 = p4[2]; pa3 = p4[3];
            const float4* q4 = (const float4*)(hrow + f0 + 32);
            pb0 = q4[0]; pb1 = q4[1]; pb2 = q4[2]; pb3 = q4[3];
        }
        __syncthreads();
        half8 af[4], bf[4];
#pragma unroll
        for (int a = 0; a < 4; a++)
            af[a] = *(const half8*)((char*)As + swz(wmh * 64 + a * 16 + l15, quad));
#pragma unroll
        for (int b = 0; b < 4; b++)
            bf[b] = *(const half8*)((char*)Bs + swz(wnh * 64 + b * 16 + l15, quad));
#pragma unroll
        for (int a = 0; a < 4; a++)
#pragma unroll
            for (int b = 0; b < 4; b++)
                acc[a][b] = __builtin_amdgcn_mfma_f32_16x16x32_f16(af[a], bf[b], acc[a][b], 0, 0, 0);
    }

    __syncthreads();   // tiles dead; overlay epilogue arrays
    if (t < 128) {
        bWs[t] = bW[head * 256 + o0 + t];
        a1s[t] = a1[head * 256 + o0 + t];
        a2s[t] = a2[head * 256 + o0 + t];
    }
    __syncthreads();

    const int bidx = bn0 >> 10;     // batch index (tile never crosses batch)
    const int nbase = bn0 & 1023;
#pragma unroll
    for (int b = 0; b < 4; b++) {
        const int bnl = wnh * 64 + b * 16 + l15;   // local bn 0..127
        const int n = nbase + bnl;
        float p1 = 0.f, p2 = 0.f;
#pragma unroll
        for (int a = 0; a < 4; a++) {
#pragma unroll
            for (int r = 0; r < 4; r++) {
                int ol = wmh * 64 + a * 16 + quad * 4 + r;   // local o
                float v = acc[a][b][r] + bWs[ol];
                WhT[(((size_t)(bidx * 8 + head) * 256 + o0 + ol) << 10) + n] = (_Float16)v;
                p1 = fmaf(v, a1s[ol], p1);
                p2 = fmaf(v, a2s[ol], p2);
            }
        }
        p1 += __shfl_xor(p1, 16, 64); p1 += __shfl_xor(p1, 32, 64);
        p2 += __shfl_xor(p2, 16, 64); p2 += __shfl_xor(p2, 32, 64);
        if (lane < 16) {
            part1[wmh * 128 + bnl] = p1;
            part2[wmh * 128 + bnl] = p2;
        }
    }
    __syncthreads();
    if (t < 128) {
        float s1 = part1[t] + part1[128 + t];
        float s2 = part2[t] + part2[128 + t];
        const size_t idx = (size_t)(bidx * 8 + head) * 1024 + nbase + t;
        eiP[(size_t)ot * 131072 + idx] = s1;
        ejP[(size_t)ot * 131072 + idx] = s2;
    }
}

// ---------------------------------------------------------------------------
// Stage 2: out[b,i,h*256+o] = sigmoid(relu( (1/l_i) * sum_j p~_ij * Wh[j,o] ))
// p~ = exp2(lrelu(ci+ej)*L2E - m*L2E); l_i via MFMA vs ones.
// Tile 128(i) x 128(o), K=1024 in BK=64, 256 thr = 4 waves, 4x4 tiles.
__global__ __launch_bounds__(256, 3) void pv_kernel(
    const _Float16* __restrict__ WhT, const float* __restrict__ eiP,
    const float* __restrict__ ejP, const float* __restrict__ bA,
    float* __restrict__ out)
{
    const int bh = blockIdx.x;   // 0..127 (fast dim -> XCD key)
    const int it = blockIdx.y;   // 0..7
    const int ot = blockIdx.z;   // 0..1
    const int b = bh >> 3, head = bh & 7;
    const int t = threadIdx.x;
    const int wave = t >> 6, lane = t & 63;
    const int l15 = lane & 15, quad = lane >> 4;
    const int wmh = wave & 1, wnh = wave >> 1;

    __shared__ char smem[37440];
    _Float16* Ap = (_Float16*)smem;             // P: 128 rows x 128B = 16384
    _Float16* Bp = (_Float16*)(smem + 16384);   // WhT: 128 rows x 128B = 16384
    float* ejs  = (float*)(smem + 32768);       // 1024 f32 (*L2E) 4KB
    float* lns  = (float*)(smem + 36864);       // 128 denominators
    float* wred = (float*)(smem + 37376);       // 4 wave maxes

    // preamble: ej = ej0+ej1 (ot halves), stage *L2E, block max
    const float* ej0 = ejP + bh * 1024;
    const float* ej1 = ejP + 131072 + bh * 1024;
    float mx = -1e30f;
#pragma unroll
    for (int k = 0; k < 4; k++) {
        int idx = t + k * 256;
        float v = (ej0[idx] + ej1[idx]) * L2E;
        ejs[idx] = v;
        mx = fmaxf(mx, v);
    }
#pragma unroll
    for (int m = 32; m; m >>= 1) mx = fmaxf(mx, __shfl_xor(mx, m, 64));
    if (lane == 0) wred[wave] = mx;
    __syncthreads();
    float ejmax = fmaxf(fmaxf(wred[0], wred[1]), fmaxf(wred[2], wred[3]));

    const int i0 = it * 128, o0 = ot * 128;
    const int prow = t >> 1, pjh = t & 1;   // P-gen: row, 32-j half
    const float cip = (eiP[bh * 1024 + i0 + prow] +
                       eiP[131072 + bh * 1024 + i0 + prow] + bA[head]) * L2E;
    const float tmv = cip + ejmax;
    const float nm = -fmaxf(tmv, 0.2f * tmv);   // -m*log2e

    const int wr_ = t >> 1, hh = t & 1;   // B staging: row(o), 64B half
    const _Float16* wrow = WhT + ((size_t)bh << 18) + ((size_t)(o0 + wr_) << 10) + hh * 32;

    floatx4 acc[4][4], accl[4];
#pragma unroll
    for (int a = 0; a < 4; a++) {
        accl[a] = (floatx4)0.0f;
#pragma unroll
        for (int c = 0; c < 4; c++) acc[a][c] = (floatx4)0.0f;
    }
    const bool doL = (wnh == 0);
    const half8 ones = {1, 1, 1, 1, 1, 1, 1, 1};

    uint4 w0, w1, w2, w3;
    { const uint4* s = (const uint4*)wrow; w0 = s[0]; w1 = s[1]; w2 = s[2]; w3 = s[3]; }

    for (int j0 = 0; j0 < 1024; j0 += 64) {
        __syncthreads();
        {   // P-gen: 32 exps -> 4 swizzled uint4 (ej read = LDS broadcast)
            const float4* ejp4 = (const float4*)(ejs + j0 + pjh * 32);
#pragma unroll
            for (int q = 0; q < 4; q++) {
                float4 e4a = ejp4[2 * q], e4b = ejp4[2 * q + 1];
                float p[8];
                const float ev[8] = {e4a.x, e4a.y, e4a.z, e4a.w,
                                     e4b.x, e4b.y, e4b.z, e4b.w};
#pragma unroll
                for (int u = 0; u < 8; u++) {
                    float e = cip + ev[u];
                    float lr = fmaxf(e, 0.2f * e);
                    p[u] = EXP2F(lr + nm);
                }
                *(uint4*)((char*)Ap + swz128(prow, pjh * 4 + q)) =
                    make_uint4(pack2(p[0], p[1]), pack2(p[2], p[3]),
                               pack2(p[4], p[5]), pack2(p[6], p[7]));
            }
        }
        {   // B staging: 64B per thread
            const int c0 = 4 * hh;
            *(uint4*)((char*)Bp + swz128(wr_, c0))     = w0;
            *(uint4*)((char*)Bp + swz128(wr_, c0 + 1)) = w1;
            *(uint4*)((char*)Bp + swz128(wr_, c0 + 2)) = w2;
            *(uint4*)((char*)Bp + swz128(wr_, c0 + 3)) = w3;
        }
        if (j0 < 960) {   // prefetch next 64-j chunk
            const uint4* s = (const uint4*)(wrow + j0 + 64);
            w0 = s[0]; w1 = s[1]; w2 = s[2]; w3 = s[3];
        }
        __syncthreads();
#pragma unroll
        for (int kk = 0; kk < 2; kk++) {
            half8 af[4], bf[4];
#pragma unroll
            for (int a = 0; a < 4; a++)
                af[a] = *(const half8*)((char*)Ap + swz128(wmh * 64 + a * 16 + l15, kk * 4 + quad));
#pragma unroll
            for (int c = 0; c < 4; c++)
                bf[c] = *(const half8*)((char*)Bp + swz128(wnh * 64 + c * 16 + l15, kk * 4 + quad));
            if (doL) {
#pragma unroll
                for (int a = 0; a < 4; a++)
                    accl[a] = __builtin_amdgcn_mfma_f32_16x16x32_f16(af[a], ones, accl[a], 0, 0, 0);
            }
#pragma unroll
            for (int a = 0; a < 4; a++)
#pragma unroll
                for (int c = 0; c < 4; c++)
                    acc[a][c] = __builtin_amdgcn_mfma_f32_16x16x32_f16(af[a], bf[c], acc[a][c], 0, 0, 0);
        }
    }

    __syncthreads();
    if (doL && l15 == 0) {   // all 16 cols identical; publish row sums
#pragma unroll
        for (int a = 0; a < 4; a++)
#pragma unroll
            for (int r = 0; r < 4; r++)
                lns[wmh * 64 + a * 16 + quad * 4 + r] = accl[a][r];
    }
    __syncthreads();

    float rinv[4][4];
#pragma unroll
    for (int a = 0; a < 4; a++)
#pragma unroll
        for (int r = 0; r < 4; r++)
            rinv[a][r] = 1.0f / lns[wmh * 64 + a * 16 + quad * 4 + r];

#pragma unroll
    for (int a = 0; a < 4; a++) {
#pragma unroll
        for (int c = 0; c < 4; c++) {
            int o = o0 + wnh * 64 + c * 16 + l15;
#pragma unroll
            for (int r = 0; r < 4; r++) {
                int i = i0 + wmh * 64 + a * 16 + quad * 4 + r;
                float v = acc[a][c][r] * rinv[a][r];
                float rl = fmaxf(v, 0.0f);
                float y = 1.0f / (1.0f + EXP2F(-rl * L2E));
                out[((size_t)(b * 1024 + i) << 11) + head * 256 + o] = y;
            }
        }
    }
}

// ---------------------------------------------------------------------------
extern "C" void kernel_launch(void* const* d_in, const int* in_sizes, int n_in,
                              void* d_out, int out_size, void* d_ws, size_t ws_size,
                              hipStream_t stream)
{
    const float* h  = (const float*)d_in[0];
    const float* W  = (const float*)d_in[1];
    const float* bW = (const float*)d_in[2];
    const float* a1 = (const float*)d_in[3];
    const float* a2 = (const float*)d_in[4];
    const float* bA = (const float*)d_in[5];
    float* out = (float*)d_out;

    char* ws = (char*)d_ws;
    _Float16* WhT = (_Float16*)ws;                       // 67108864 B
    float* eiP = (float*)(ws + 67108864);                // 2 x 524288 B
    float* ejP = (float*)(ws + 67108864 + 1048576);      // 2 x 524288 B

    hipLaunchKernelGGL(wh_kernel, dim3(128, 2, 8), dim3(256), 0, stream,
                       h, W, bW, WhT, a1, a2, eiP, ejP);
    hipLaunchKernelGGL(pv_kernel, dim3(128, 8, 2), dim3(256), 0, stream,
                       WhT, eiP, ejP, bA, out);
}